// Round 1
// baseline (1323.589 us; speedup 1.0000x reference)
//
#include <hip/hip_runtime.h>

#define T_TOKENS 4096   // B*S
#define DIM      1024   // D
#define NEXP     8      // E
#define FDIM     4096   // F
#define NASSIGN  8192   // T_TOKENS * K
#define PADROWS  8320   // NASSIGN + 128 tile padding

typedef __bf16 bf16x8 __attribute__((ext_vector_type(8)));
typedef float  f32x4  __attribute__((ext_vector_type(4)));

__device__ __forceinline__ unsigned short f2b(float f) {
  unsigned u = __builtin_bit_cast(unsigned, f);
  u = u + 0x7fffu + ((u >> 16) & 1u);   // RNE, finite inputs only
  return (unsigned short)(u >> 16);
}
__device__ __forceinline__ float b2f(unsigned short h) {
  unsigned u = ((unsigned)h) << 16;
  return __builtin_bit_cast(float, u);
}
__device__ __forceinline__ void gload_lds16(const void* g, void* l) {
  __builtin_amdgcn_global_load_lds(
      (const __attribute__((address_space(1))) void*)g,
      (__attribute__((address_space(3))) void*)l, 16, 0, 0);
}

// ---------------- router: logits -> softmax -> top2 -> weights ----------------
__global__ void router_kernel(const float* __restrict__ x, const float* __restrict__ rw,
                              const float* __restrict__ rb, int* __restrict__ tidx,
                              float* __restrict__ tw, int* __restrict__ counts) {
  int gid = blockIdx.x * blockDim.x + threadIdx.x;
  int t = gid >> 6;
  int lane = threadIdx.x & 63;
  if (t >= T_TOKENS) return;
  const float* xr = x + (size_t)t * DIM;
  float acc[NEXP];
#pragma unroll
  for (int e = 0; e < NEXP; ++e) acc[e] = 0.f;
  for (int d = lane; d < DIM; d += 64) {
    float xv = xr[d];
    const float* r = rw + (size_t)d * NEXP;
#pragma unroll
    for (int e = 0; e < NEXP; ++e) acc[e] += xv * r[e];
  }
#pragma unroll
  for (int e = 0; e < NEXP; ++e) {
#pragma unroll
    for (int off = 32; off > 0; off >>= 1) acc[e] += __shfl_xor(acc[e], off);
  }
  if (lane == 0) {
    float lg[NEXP], m = -1e30f;
#pragma unroll
    for (int e = 0; e < NEXP; ++e) { lg[e] = acc[e] + rb[e]; m = fmaxf(m, lg[e]); }
    float p[NEXP], Z = 0.f;
#pragma unroll
    for (int e = 0; e < NEXP; ++e) { p[e] = expf(lg[e] - m); Z += p[e]; }
    int i0 = 0;
#pragma unroll
    for (int e = 1; e < NEXP; ++e) if (p[e] > p[i0]) i0 = e;
    int i1 = (i0 == 0) ? 1 : 0;
#pragma unroll
    for (int e = 0; e < NEXP; ++e) if (e != i0 && p[e] > p[i1]) i1 = e;
    float q0 = p[i0] / Z, q1 = p[i1] / Z;
    float s = q0 + q1 + 1e-8f;
    tidx[t * 2] = i0; tidx[t * 2 + 1] = i1;
    tw[t * 2] = q0 / s; tw[t * 2 + 1] = q1 / s;
    atomicAdd(&counts[i0], 1); atomicAdd(&counts[i1], 1);
  }
}

// ---------------- tiny scan: counts -> offsets, init cursors ----------------
__global__ void scan_kernel(const int* __restrict__ counts, int* __restrict__ offsets,
                            int* __restrict__ cursors) {
  if (threadIdx.x == 0) {
    int s = 0;
    for (int e = 0; e < NEXP; ++e) { offsets[e] = s; cursors[e] = s; s += counts[e]; }
    offsets[NEXP] = s;
  }
}

// ---------------- gather x rows (fp32 -> bf16) into expert-segmented Xg ----------------
__global__ void gather_kernel(const float* __restrict__ x, const int* __restrict__ tidx,
                              int* __restrict__ cursors, int* __restrict__ tslot,
                              unsigned short* __restrict__ Xg) {
  int aid = (blockIdx.x * blockDim.x + threadIdx.x) >> 6;
  int lane = threadIdx.x & 63;
  if (aid >= NASSIGN) return;
  int t = aid >> 1, k = aid & 1;
  int e = tidx[t * 2 + k];
  int slot = 0;
  if (lane == 0) {
    slot = atomicAdd(&cursors[e], 1);
    tslot[t * 2 + k] = slot;
  }
  slot = __shfl(slot, 0);
  const float4* xr = (const float4*)(x + (size_t)t * DIM);
  ushort4* dst = (ushort4*)(Xg + (size_t)slot * DIM);
#pragma unroll
  for (int i = 0; i < 4; ++i) {
    int idx = i * 64 + lane;
    float4 v = xr[idx];
    ushort4 o;
    o.x = f2b(v.x); o.y = f2b(v.y); o.z = f2b(v.z); o.w = f2b(v.w);
    dst[idx] = o;
  }
}

// ---------------- transpose + convert: src [E][R][C] f32 -> dst [E][C][R] bf16 ----------------
__global__ void transpose_cvt(const float* __restrict__ src, unsigned short* __restrict__ dst,
                              int R, int C) {
  __shared__ unsigned short tile[64][72];
  int e = blockIdx.z;
  const float* s = src + (size_t)e * R * C;
  unsigned short* d = dst + (size_t)e * R * C;
  int c0 = blockIdx.x * 64, r0 = blockIdx.y * 64;
  int tx = threadIdx.x & 15, ty = threadIdx.x >> 4;
#pragma unroll
  for (int i = 0; i < 4; ++i) {
    int r = i * 16 + ty;
    float4 v = *(const float4*)(s + (size_t)(r0 + r) * C + c0 + tx * 4);
    tile[r][tx * 4 + 0] = f2b(v.x);
    tile[r][tx * 4 + 1] = f2b(v.y);
    tile[r][tx * 4 + 2] = f2b(v.z);
    tile[r][tx * 4 + 3] = f2b(v.w);
  }
  __syncthreads();
#pragma unroll
  for (int i = 0; i < 4; ++i) {
    int c = i * 16 + ty;
    ushort4 o;
    o.x = tile[tx * 4 + 0][c];
    o.y = tile[tx * 4 + 1][c];
    o.z = tile[tx * 4 + 2][c];
    o.w = tile[tx * 4 + 3][c];
    *(ushort4*)(d + (size_t)(c0 + c) * R + r0 + tx * 4) = o;
  }
}

// ---------------- per-expert GEMM: C[m][n] = act(A[m][:] . B[n][:] + bias[n]) ----------------
// A: [slots][K] bf16 (expert segment rows), B: [E][N][K] bf16, Out: [slots][N] bf16
template <bool GELU>
__global__ __launch_bounds__(256) void ffn_gemm(
    const unsigned short* __restrict__ A, const unsigned short* __restrict__ Bw,
    const float* __restrict__ bias, unsigned short* __restrict__ Out,
    const int* __restrict__ offsets, int N, int K) {
  int e = blockIdx.z;
  int off = offsets[e];
  int n_e = offsets[e + 1] - off;
  int mt = blockIdx.x;
  if (mt * 128 >= n_e) return;
  int row0 = off + mt * 128;
  int rows_valid = n_e - mt * 128;
  if (rows_valid > 128) rows_valid = 128;
  int n0 = blockIdx.y * 128;

  __shared__ unsigned short As[128 * 64];
  __shared__ unsigned short Bs[128 * 64];

  int tid = threadIdx.x, w = tid >> 6, l = tid & 63;
  int wm = w >> 1, wn = w & 1;

  f32x4 acc[4][4] = {};

  const unsigned short* Ab = A + (size_t)row0 * K;
  const unsigned short* Bb = Bw + (size_t)e * N * K + (size_t)n0 * K;
  int sr = l >> 3;          // row within 8-row group
  int sc = (l & 7) * 8;     // bf16 elems (16B chunk)

  for (int k0 = 0; k0 < K; k0 += 64) {
#pragma unroll
    for (int i = 0; i < 4; ++i) {
      int r = w * 32 + i * 8;
      gload_lds16(Ab + (size_t)(r + sr) * K + k0 + sc, &As[r * 64]);
      gload_lds16(Bb + (size_t)(r + sr) * K + k0 + sc, &Bs[r * 64]);
    }
    __syncthreads();
#pragma unroll
    for (int kk = 0; kk < 2; ++kk) {
      bf16x8 af[4], bfr[4];
#pragma unroll
      for (int i = 0; i < 4; ++i) {
        af[i]  = *(const bf16x8*)&As[(wm * 64 + i * 16 + (l & 15)) * 64 + kk * 32 + (l >> 4) * 8];
        bfr[i] = *(const bf16x8*)&Bs[(wn * 64 + i * 16 + (l & 15)) * 64 + kk * 32 + (l >> 4) * 8];
      }
#pragma unroll
      for (int i = 0; i < 4; ++i)
#pragma unroll
        for (int j = 0; j < 4; ++j)
          acc[i][j] = __builtin_amdgcn_mfma_f32_16x16x32_bf16(af[i], bfr[j], acc[i][j], 0, 0, 0);
    }
    __syncthreads();
  }

  int cr = (l >> 4) * 4, cc = l & 15;
#pragma unroll
  for (int i = 0; i < 4; ++i) {
#pragma unroll
    for (int r = 0; r < 4; ++r) {
      int rl = wm * 64 + i * 16 + cr + r;
      if (rl < rows_valid) {
        size_t rowbase = (size_t)(row0 + rl) * N;
#pragma unroll
        for (int j = 0; j < 4; ++j) {
          int col = n0 + wn * 64 + j * 16 + cc;
          float v = acc[i][j][r] + bias[(size_t)e * N + col];
          if (GELU) v = 0.5f * v * (1.0f + erff(v * 0.70710678118654752f));
          Out[rowbase + col] = f2b(v);
        }
      }
    }
  }
}

// ---------------- combine: out = x + w0*EO[slot0] + w1*EO[slot1] ----------------
__global__ void combine_kernel(const float* __restrict__ x, const unsigned short* __restrict__ EO,
                               const int* __restrict__ tslot, const float* __restrict__ tw,
                               float* __restrict__ out) {
  int t = blockIdx.x;
  int s0 = tslot[t * 2], s1 = tslot[t * 2 + 1];
  float w0 = tw[t * 2], w1 = tw[t * 2 + 1];
  int i = threadIdx.x;  // float4 index, 256 * 4 = 1024 elems
  float4 xv = ((const float4*)(x + (size_t)t * DIM))[i];
  ushort4 a = ((const ushort4*)(EO + (size_t)s0 * DIM))[i];
  ushort4 b = ((const ushort4*)(EO + (size_t)s1 * DIM))[i];
  float4 o;
  o.x = xv.x + w0 * b2f(a.x) + w1 * b2f(b.x);
  o.y = xv.y + w0 * b2f(a.y) + w1 * b2f(b.y);
  o.z = xv.z + w0 * b2f(a.z) + w1 * b2f(b.z);
  o.w = xv.w + w0 * b2f(a.w) + w1 * b2f(b.w);
  ((float4*)(out + (size_t)t * DIM))[i] = o;
}

extern "C" void kernel_launch(void* const* d_in, const int* in_sizes, int n_in,
                              void* d_out, int out_size, void* d_ws, size_t ws_size,
                              hipStream_t stream) {
  const float* x        = (const float*)d_in[0];
  const float* router_w = (const float*)d_in[1];
  const float* router_b = (const float*)d_in[2];
  const float* w1       = (const float*)d_in[3];
  const float* b1       = (const float*)d_in[4];
  const float* w2       = (const float*)d_in[5];
  const float* b2       = (const float*)d_in[6];
  float* out = (float*)d_out;
  char* ws = (char*)d_ws;

  // workspace layout (bytes)
  int*   counts  = (int*)(ws + 0);
  int*   cursors = (int*)(ws + 64);
  int*   offsets = (int*)(ws + 128);
  int*   tidx    = (int*)(ws + 256);
  float* tw      = (float*)(ws + 256 + 32768);
  int*   tslot   = (int*)(ws + 256 + 65536);
  const size_t XG_OFF  = 1u << 20;
  const size_t XG_B    = (size_t)PADROWS * DIM * 2;        // 17,039,360
  const size_t H_OFF   = XG_OFF + XG_B;
  const size_t H_B     = (size_t)PADROWS * FDIM * 2;       // 68,157,440
  const size_t EO_OFF  = H_OFF + H_B;
  const size_t EO_B    = XG_B;
  const size_t W1T_OFF = EO_OFF + EO_B;
  const size_t WT_B    = (size_t)NEXP * DIM * FDIM * 2;    // 67,108,864
  const size_t W2T_OFF = W1T_OFF + WT_B;
  unsigned short* Xg  = (unsigned short*)(ws + XG_OFF);
  unsigned short* H   = (unsigned short*)(ws + H_OFF);
  unsigned short* EO  = (unsigned short*)(ws + EO_OFF);
  unsigned short* W1T = (unsigned short*)(ws + W1T_OFF);
  unsigned short* W2T = (unsigned short*)(ws + W2T_OFF);

  hipMemsetAsync(ws, 0, 256, stream);
  router_kernel<<<T_TOKENS / 4, 256, 0, stream>>>(x, router_w, router_b, tidx, tw, counts);
  scan_kernel<<<1, 64, 0, stream>>>(counts, offsets, cursors);
  gather_kernel<<<NASSIGN / 4, 256, 0, stream>>>(x, tidx, cursors, tslot, Xg);
  // W1 [E][1024][4096] -> W1T [E][4096][1024]
  transpose_cvt<<<dim3(FDIM / 64, DIM / 64, NEXP), 256, 0, stream>>>(w1, W1T, DIM, FDIM);
  // W2 [E][4096][1024] -> W2T [E][1024][4096]
  transpose_cvt<<<dim3(DIM / 64, FDIM / 64, NEXP), 256, 0, stream>>>(w2, W2T, FDIM, DIM);
  // H = gelu(Xg @ W1 + b1)
  ffn_gemm<true><<<dim3(32, FDIM / 128, NEXP), 256, 0, stream>>>(Xg, W1T, b1, H, offsets, FDIM, DIM);
  // EO = H @ W2 + b2
  ffn_gemm<false><<<dim3(32, DIM / 128, NEXP), 256, 0, stream>>>(H, W2T, b2, EO, offsets, DIM, FDIM);
  combine_kernel<<<T_TOKENS, 256, 0, stream>>>(x, EO, tslot, tw, out);
}